// Round 2
// baseline (1135.514 us; speedup 1.0000x reference)
//
#include <hip/hip_runtime.h>

#define D_MODEL 2048
#define SEQ     2048
#define BATCH   4
#define NQKV    (3 * D_MODEL)   // 6144

typedef __attribute__((ext_vector_type(8))) short bf16x8;
typedef __attribute__((ext_vector_type(4))) float floatx4;

__device__ __forceinline__ unsigned short f2b(float f) {
    unsigned x = __builtin_bit_cast(unsigned, f);
    x += 0x7fffu + ((x >> 16) & 1u);   // round-to-nearest-even
    return (unsigned short)(x >> 16);
}

__device__ __forceinline__ void storeC(float* p, float v) { *p = v; }
__device__ __forceinline__ void storeC(unsigned short* p, float v) { *p = f2b(v); }

__device__ __forceinline__ void gload_lds16(const void* g, void* l) {
    __builtin_amdgcn_global_load_lds(
        (const __attribute__((address_space(1))) void*)g,
        (__attribute__((address_space(3))) void*)l,
        16, 0, 0);
}

// ---------------------------------------------------------------------------
// BT GEMM: C[m,n] = (sum_k A[m,k]*B[n,k]) (+bias[n]) (*scale); A,B bf16 k-major
// 128x128 tile, BK=32, 256 threads (4 waves, 4x4 of mfma 16x16x32 bf16 each)
// EPI: 0 = +bias[n], 1 = *scale, 2 = plain.  CT: float (f32 out) or ushort.
// ---------------------------------------------------------------------------
template <int EPI, typename CT>
__global__ __launch_bounds__(256) void gemm_bt(
    const unsigned short* __restrict__ A, int lda,
    const unsigned short* __restrict__ B, int ldb,
    CT* __restrict__ C, int ldc,
    int K, const float* __restrict__ bias, float scale)
{
    __shared__ __align__(16) unsigned short As[128 * 32];
    __shared__ __align__(16) unsigned short Bs[128 * 32];

    const int t = threadIdx.x;
    const long long tM = (long long)blockIdx.y * 128;
    const long long tN = (long long)blockIdx.x * 128;

    // staging: thread t loads 16B from row (t>>2), k-chunk (t&3)*8.
    // LDS dest = wave-uniform base + lane*16B  ->  As[t*8]
    const int ldr = t >> 2;
    const int kof = (t & 3) * 8;
    const unsigned short* ga = A + (tM + ldr) * lda + kof;
    const unsigned short* gb = B + (tN + ldr) * ldb + kof;
    unsigned short* lAs = &As[(t >> 6) * 512];
    unsigned short* lBs = &Bs[(t >> 6) * 512];
    const long long lda64 = (long long)64 * lda;
    const long long ldb64 = (long long)64 * ldb;

    const int l    = t & 63;
    const int w    = t >> 6;
    const int wm   = (w >> 1) * 64;
    const int wn   = (w & 1) * 64;
    const int quad = l >> 4;
    const int r16  = l & 15;

    floatx4 acc[4][4];
#pragma unroll
    for (int i = 0; i < 4; ++i)
#pragma unroll
        for (int j = 0; j < 4; ++j)
            acc[i][j] = (floatx4){0.f, 0.f, 0.f, 0.f};

    for (int k0 = 0; k0 < K; k0 += 32) {
        gload_lds16(ga + k0,         lAs);
        gload_lds16(ga + lda64 + k0, lAs + 2048);
        gload_lds16(gb + k0,         lBs);
        gload_lds16(gb + ldb64 + k0, lBs + 2048);
        __syncthreads();

        bf16x8 af[4], bfr[4];
#pragma unroll
        for (int mi = 0; mi < 4; ++mi)
            af[mi] = *(const bf16x8*)&As[(wm + mi * 16 + r16) * 32 + quad * 8];
#pragma unroll
        for (int ni = 0; ni < 4; ++ni)
            bfr[ni] = *(const bf16x8*)&Bs[(wn + ni * 16 + r16) * 32 + quad * 8];
#pragma unroll
        for (int mi = 0; mi < 4; ++mi)
#pragma unroll
            for (int ni = 0; ni < 4; ++ni)
                acc[mi][ni] = __builtin_amdgcn_mfma_f32_16x16x32_bf16(
                    af[mi], bfr[ni], acc[mi][ni], 0, 0, 0);
        __syncthreads();
    }

    // C/D layout: col = lane&15, row = (lane>>4)*4 + reg
#pragma unroll
    for (int mi = 0; mi < 4; ++mi) {
#pragma unroll
        for (int ni = 0; ni < 4; ++ni) {
            const long long row = tM + wm + mi * 16 + quad * 4;
            const int col = (int)tN + wn + ni * 16 + r16;
            float badd = 0.f;
            if (EPI == 0) badd = bias[col];
#pragma unroll
            for (int r = 0; r < 4; ++r) {
                float v = acc[mi][ni][r] + badd;
                if (EPI == 1) v *= scale;
                storeC(&C[(row + r) * ldc + col], v);
            }
        }
    }
}

// f32 -> bf16 bulk convert (n divisible by 1024)
__global__ void cvt_f32_bf16(const float* __restrict__ in,
                             unsigned short* __restrict__ out, long long n)
{
    long long i = ((long long)blockIdx.x * 256 + threadIdx.x) * 4;
    if (i + 3 < n) {
        float4 v = *(const float4*)(in + i);
        ushort4 o;
        o.x = f2b(v.x); o.y = f2b(v.y); o.z = f2b(v.z); o.w = f2b(v.w);
        *(ushort4*)(out + i) = o;
    }
}

// W_qkv f32 [2048, 6144] (f = 3*d + sel fastest) -> Wqkv_t bf16 [6144, 2048],
// Wqkv_t[sel*2048 + d][k] = W_qkv[k][3*d + sel]
__global__ void deint_wqkv(const float* __restrict__ W,
                           unsigned short* __restrict__ Wt)
{
    __shared__ unsigned short tile[32][102];   // stride 204B -> conflict-free
    const int d0 = blockIdx.x * 32;
    const int k0 = blockIdx.y * 32;
    const int t = threadIdx.x;

    for (int i = t; i < 32 * 96; i += 256) {
        int r = i / 96, c = i % 96;
        tile[r][c] = f2b(W[(long long)(k0 + r) * NQKV + 3 * d0 + c]);
    }
    __syncthreads();

    const int k = t & 31;
    const int dx0 = t >> 5;
#pragma unroll
    for (int sel = 0; sel < 3; ++sel)
#pragma unroll
        for (int it = 0; it < 4; ++it) {
            int dx = dx0 + it * 8;
            Wt[(long long)(sel * 2048 + d0 + dx) * D_MODEL + k0 + k] =
                tile[k][3 * dx + sel];
        }
}

// W_fc f32 [2048, 2048] -> Wfc_t bf16, Wfc_t[n][k] = W_fc[k][n]
__global__ void transpose_wfc(const float* __restrict__ W,
                              unsigned short* __restrict__ Wt)
{
    __shared__ unsigned short tile[32][34];    // stride 68B -> conflict-free
    const int n0 = blockIdx.x * 32;
    const int k0 = blockIdx.y * 32;
    const int t = threadIdx.x;
    const int c = t & 31;
    const int r0 = t >> 5;
#pragma unroll
    for (int it = 0; it < 4; ++it) {
        int r = r0 + it * 8;
        tile[r][c] = f2b(W[(long long)(k0 + r) * D_MODEL + n0 + c]);
    }
    __syncthreads();
#pragma unroll
    for (int it = 0; it < 4; ++it) {
        int r = r0 + it * 8;
        Wt[(long long)(n0 + r) * D_MODEL + k0 + c] = tile[c][r];
    }
}

// bias deinterleave (f32 -> f32): bias_qkv_t[sel*2048+d] = bqkv[3*d+sel]
__global__ void prep_bias(const float* __restrict__ bqkv,
                          const float* __restrict__ bfc,
                          float* __restrict__ bias_qkv_t,
                          float* __restrict__ bias_fc)
{
    int i = blockIdx.x * 256 + threadIdx.x;
    if (i < NQKV) {
        int sel = i >> 11, d = i & 2047;
        bias_qkv_t[i] = bqkv[3 * d + sel];
    } else if (i < NQKV + D_MODEL) {
        bias_fc[i - NQKV] = bfc[i - NQKV];
    }
}

extern "C" void kernel_launch(void* const* d_in, const int* in_sizes, int n_in,
                              void* d_out, int out_size, void* d_ws, size_t ws_size,
                              hipStream_t stream)
{
    (void)in_sizes; (void)n_in; (void)out_size; (void)ws_size;

    const float* x    = (const float*)d_in[0];
    const float* Wqkv = (const float*)d_in[1];
    const float* bqkv = (const float*)d_in[2];
    const float* Wfc  = (const float*)d_in[3];
    const float* bfc  = (const float*)d_in[4];
    float* out = (float*)d_out;

    char* ws = (char*)d_ws;
    size_t off = 0;
    auto alloc = [&](size_t bytes) {
        void* p = ws + off;
        off += (bytes + 255) & ~(size_t)255;
        return p;
    };
    // bf16 workspace buffers (per-batch reuse for QKV/S/A): ~110 MB total
    unsigned short* xb     = (unsigned short*)alloc((size_t)BATCH * SEQ * D_MODEL * 2);
    unsigned short* Wqkv_t = (unsigned short*)alloc((size_t)NQKV * D_MODEL * 2);
    unsigned short* Wfc_t  = (unsigned short*)alloc((size_t)D_MODEL * D_MODEL * 2);
    unsigned short* QKVb   = (unsigned short*)alloc((size_t)SEQ * NQKV * 2);
    unsigned short* Sb     = (unsigned short*)alloc((size_t)SEQ * SEQ * 2);
    unsigned short* Ab     = (unsigned short*)alloc((size_t)SEQ * SEQ * 2);
    float* bias_qkv = (float*)alloc((size_t)NQKV * 4);
    float* bias_fc  = (float*)alloc((size_t)D_MODEL * 4);

    const long long nx = (long long)BATCH * SEQ * D_MODEL;  // 16.8M
    cvt_f32_bf16<<<(int)(nx / 1024), 256, 0, stream>>>(x, xb, nx);
    deint_wqkv<<<dim3(64, 64), 256, 0, stream>>>(Wqkv, Wqkv_t);
    transpose_wfc<<<dim3(64, 64), 256, 0, stream>>>(Wfc, Wfc_t);
    prep_bias<<<32, 256, 0, stream>>>(bqkv, bfc, bias_qkv, bias_fc);

    const float scale = 0.02209708691207961f;  // 2048^-0.5

    for (int b = 0; b < BATCH; ++b) {
        const unsigned short* xb_b = xb + (long long)b * SEQ * D_MODEL;
        float* out_b = out + (long long)b * SEQ * D_MODEL;

        // 1) QKV_b = x_b @ Wqkv_t^T + bias    [2048 x 6144]
        gemm_bt<0, unsigned short><<<dim3(NQKV / 128, SEQ / 128), 256, 0, stream>>>(
            xb_b, D_MODEL, Wqkv_t, D_MODEL, QKVb, NQKV, D_MODEL, bias_qkv, 1.f);
        // 2) S_b = Q_b @ K_b^T * scale        [2048 x 2048]
        gemm_bt<1, unsigned short><<<dim3(SEQ / 128, SEQ / 128), 256, 0, stream>>>(
            QKVb, NQKV, QKVb + D_MODEL, NQKV, Sb, SEQ, D_MODEL, nullptr, scale);
        // 3) A_b = S_b @ V_b^T                [2048 x 2048]
        gemm_bt<2, unsigned short><<<dim3(SEQ / 128, SEQ / 128), 256, 0, stream>>>(
            Sb, SEQ, QKVb + 2 * D_MODEL, NQKV, Ab, SEQ, SEQ, nullptr, 1.f);
        // 4) out_b = A_b @ Wfc_t^T + bias_fc  [2048 x 2048] f32 out
        gemm_bt<0, float><<<dim3(D_MODEL / 128, SEQ / 128), 256, 0, stream>>>(
            Ab, SEQ, Wfc_t, D_MODEL, out_b, D_MODEL, SEQ, bias_fc, 1.f);
    }
}

// Round 3
// 778.963 us; speedup vs baseline: 1.4577x; 1.4577x over previous
//
#include <hip/hip_runtime.h>

#define D_MODEL 2048
#define SEQ     2048
#define BATCH   4
#define MTOT    (BATCH * SEQ)   // 8192
#define NQKV    (3 * D_MODEL)   // 6144

typedef __attribute__((ext_vector_type(8))) short bf16x8;
typedef __attribute__((ext_vector_type(4))) float floatx4;

__device__ __forceinline__ unsigned short f2b(float f) {
    unsigned x = __builtin_bit_cast(unsigned, f);
    x += 0x7fffu + ((x >> 16) & 1u);   // round-to-nearest-even
    return (unsigned short)(x >> 16);
}

__device__ __forceinline__ void storeC(float* p, float v) { *p = v; }
__device__ __forceinline__ void storeC(unsigned short* p, float v) { *p = f2b(v); }

__device__ __forceinline__ void gload_lds16(const void* g, void* l) {
    __builtin_amdgcn_global_load_lds(
        (const __attribute__((address_space(1))) void*)g,
        (__attribute__((address_space(3))) void*)l,
        16, 0, 0);
}

// ---------------------------------------------------------------------------
// BT GEMM (z-batched): C[m,n] = (sum_k A[m,k]*B[n,k]) (+bias[n]) (*scale)
// A,B bf16 k-major. 128x128 tile, BK=32, 256 thr (4 waves, 4x4 mfma 16x16x32)
// EPI: 0 = +bias[n], 1 = *scale, 2 = plain.  CT: float or ushort output.
// ---------------------------------------------------------------------------
template <int EPI, typename CT>
__global__ __launch_bounds__(256) void gemm_bt(
    const unsigned short* __restrict__ A, int lda, long long strA,
    const unsigned short* __restrict__ B, int ldb, long long strB,
    CT* __restrict__ C, int ldc, long long strC,
    int K, const float* __restrict__ bias, float scale)
{
    __shared__ __align__(16) unsigned short As[128 * 32];
    __shared__ __align__(16) unsigned short Bs[128 * 32];

    const int t = threadIdx.x;
    const int bz = blockIdx.z;
    A += (long long)bz * strA;
    B += (long long)bz * strB;
    C += (long long)bz * strC;

    const long long tM = (long long)blockIdx.y * 128;
    const long long tN = (long long)blockIdx.x * 128;

    // staging: thread t loads 16B from row (t>>2), k-chunk (t&3)*8.
    // LDS dest = wave-uniform base + lane*16B  ->  As[t*8]
    const int ldr = t >> 2;
    const int kof = (t & 3) * 8;
    const unsigned short* ga = A + (tM + ldr) * lda + kof;
    const unsigned short* gb = B + (tN + ldr) * ldb + kof;
    unsigned short* lAs = &As[(t >> 6) * 512];
    unsigned short* lBs = &Bs[(t >> 6) * 512];
    const long long lda64 = (long long)64 * lda;
    const long long ldb64 = (long long)64 * ldb;

    const int l    = t & 63;
    const int w    = t >> 6;
    const int wm   = (w >> 1) * 64;
    const int wn   = (w & 1) * 64;
    const int quad = l >> 4;
    const int r16  = l & 15;

    floatx4 acc[4][4];
#pragma unroll
    for (int i = 0; i < 4; ++i)
#pragma unroll
        for (int j = 0; j < 4; ++j)
            acc[i][j] = (floatx4){0.f, 0.f, 0.f, 0.f};

    for (int k0 = 0; k0 < K; k0 += 32) {
        gload_lds16(ga + k0,         lAs);
        gload_lds16(ga + lda64 + k0, lAs + 2048);
        gload_lds16(gb + k0,         lBs);
        gload_lds16(gb + ldb64 + k0, lBs + 2048);
        __syncthreads();

        bf16x8 af[4], bfr[4];
#pragma unroll
        for (int mi = 0; mi < 4; ++mi)
            af[mi] = *(const bf16x8*)&As[(wm + mi * 16 + r16) * 32 + quad * 8];
#pragma unroll
        for (int ni = 0; ni < 4; ++ni)
            bfr[ni] = *(const bf16x8*)&Bs[(wn + ni * 16 + r16) * 32 + quad * 8];
#pragma unroll
        for (int mi = 0; mi < 4; ++mi)
#pragma unroll
            for (int ni = 0; ni < 4; ++ni)
                acc[mi][ni] = __builtin_amdgcn_mfma_f32_16x16x32_bf16(
                    af[mi], bfr[ni], acc[mi][ni], 0, 0, 0);
        __syncthreads();
    }

    // C/D layout: col = lane&15, row = (lane>>4)*4 + reg
#pragma unroll
    for (int mi = 0; mi < 4; ++mi) {
#pragma unroll
        for (int ni = 0; ni < 4; ++ni) {
            const long long row = tM + wm + mi * 16 + quad * 4;
            const int col = (int)tN + wn + ni * 16 + r16;
            float badd = 0.f;
            if (EPI == 0) badd = bias[col];
#pragma unroll
            for (int r = 0; r < 4; ++r) {
                float v = acc[mi][ni][r] + badd;
                if (EPI == 1) v *= scale;
                storeC(&C[(row + r) * ldc + col], v);
            }
        }
    }
}

// f32 -> bf16 bulk convert (n divisible by 1024)
__global__ void cvt_f32_bf16(const float* __restrict__ in,
                             unsigned short* __restrict__ out, long long n)
{
    long long i = ((long long)blockIdx.x * 256 + threadIdx.x) * 4;
    if (i + 3 < n) {
        float4 v = *(const float4*)(in + i);
        ushort4 o;
        o.x = f2b(v.x); o.y = f2b(v.y); o.z = f2b(v.z); o.w = f2b(v.w);
        *(ushort4*)(out + i) = o;
    }
}

// W_qkv f32 [2048, 6144] (f = 3*d + sel fastest) -> Wqkv_t bf16 [6144, 2048],
// Wqkv_t[sel*2048 + d][k] = W_qkv[k][3*d + sel]
__global__ void deint_wqkv(const float* __restrict__ W,
                           unsigned short* __restrict__ Wt)
{
    __shared__ unsigned short tile[32][102];   // stride 204B -> conflict-free
    const int d0 = blockIdx.x * 32;
    const int k0 = blockIdx.y * 32;
    const int t = threadIdx.x;

    for (int i = t; i < 32 * 96; i += 256) {
        int r = i / 96, c = i % 96;
        tile[r][c] = f2b(W[(long long)(k0 + r) * NQKV + 3 * d0 + c]);
    }
    __syncthreads();

    const int k = t & 31;
    const int dx0 = t >> 5;
#pragma unroll
    for (int sel = 0; sel < 3; ++sel)
#pragma unroll
        for (int it = 0; it < 4; ++it) {
            int dx = dx0 + it * 8;
            Wt[(long long)(sel * 2048 + d0 + dx) * D_MODEL + k0 + k] =
                tile[k][3 * dx + sel];
        }
}

// W_fc f32 [2048, 2048] -> Wfc_t bf16, Wfc_t[n][k] = W_fc[k][n]
__global__ void transpose_wfc(const float* __restrict__ W,
                              unsigned short* __restrict__ Wt)
{
    __shared__ unsigned short tile[32][34];    // stride 68B -> conflict-free
    const int n0 = blockIdx.x * 32;
    const int k0 = blockIdx.y * 32;
    const int t = threadIdx.x;
    const int c = t & 31;
    const int r0 = t >> 5;
#pragma unroll
    for (int it = 0; it < 4; ++it) {
        int r = r0 + it * 8;
        tile[r][c] = f2b(W[(long long)(k0 + r) * D_MODEL + n0 + c]);
    }
    __syncthreads();
#pragma unroll
    for (int it = 0; it < 4; ++it) {
        int r = r0 + it * 8;
        Wt[(long long)(n0 + r) * D_MODEL + k0 + c] = tile[c][r];
    }
}

// bias deinterleave (f32 -> f32): bias_qkv_t[sel*2048+d] = bqkv[3*d+sel]
__global__ void prep_bias(const float* __restrict__ bqkv,
                          const float* __restrict__ bfc,
                          float* __restrict__ bias_qkv_t,
                          float* __restrict__ bias_fc)
{
    int i = blockIdx.x * 256 + threadIdx.x;
    if (i < NQKV) {
        int sel = i >> 11, d = i & 2047;
        bias_qkv_t[i] = bqkv[3 * d + sel];
    } else if (i < NQKV + D_MODEL) {
        bias_fc[i - NQKV] = bfc[i - NQKV];
    }
}

extern "C" void kernel_launch(void* const* d_in, const int* in_sizes, int n_in,
                              void* d_out, int out_size, void* d_ws, size_t ws_size,
                              hipStream_t stream)
{
    (void)in_sizes; (void)n_in; (void)out_size;

    const float* x    = (const float*)d_in[0];
    const float* Wqkv = (const float*)d_in[1];
    const float* bqkv = (const float*)d_in[2];
    const float* Wfc  = (const float*)d_in[3];
    const float* bfc  = (const float*)d_in[4];
    float* out = (float*)d_out;

    char* ws = (char*)d_ws;
    size_t off = 0;
    auto alloc = [&](size_t bytes) {
        void* p = ws + off;
        off += (bytes + 255) & ~(size_t)255;
        return p;
    };

    const float scale = 0.02209708691207961f;  // 2048^-0.5
    const long long nx = (long long)MTOT * D_MODEL;  // 16.8M elems

    // Batched path needs: xb 33.6 + Wfc_t 8.4 + Wqkv_t 25.2 + QKV 100.7
    //                     + S 33.6 (A aliases xb) + biases  ~= 202 MB
    const size_t NEED_BATCHED = (size_t)(33554432ull + 8388608ull + 25165824ull
                                + 100663296ull + 33554432ull + 65536ull);

    if (ws_size >= NEED_BATCHED) {
        unsigned short* xb     = (unsigned short*)alloc((size_t)MTOT * D_MODEL * 2);
        unsigned short* Wfc_t  = (unsigned short*)alloc((size_t)D_MODEL * D_MODEL * 2);
        unsigned short* Wqkv_t = (unsigned short*)alloc((size_t)NQKV * D_MODEL * 2);
        unsigned short* QKV    = (unsigned short*)alloc((size_t)MTOT * NQKV * 2);
        unsigned short* S      = (unsigned short*)alloc((size_t)BATCH * SEQ * SEQ * 2);
        float* bias_qkv = (float*)alloc((size_t)NQKV * 4);
        float* bias_fc  = (float*)alloc((size_t)D_MODEL * 4);
        unsigned short* Abuf = xb;   // xb dead after stage 1

        cvt_f32_bf16<<<(int)(nx / 1024), 256, 0, stream>>>(x, xb, nx);
        deint_wqkv<<<dim3(64, 64), 256, 0, stream>>>(Wqkv, Wqkv_t);
        transpose_wfc<<<dim3(64, 64), 256, 0, stream>>>(Wfc, Wfc_t);
        prep_bias<<<32, 256, 0, stream>>>(bqkv, bfc, bias_qkv, bias_fc);

        const long long sQKV = (long long)SEQ * NQKV;
        const long long sS   = (long long)SEQ * SEQ;

        // 1) QKV = xb @ Wqkv_t^T + bias   [8192 x 6144], one launch
        gemm_bt<0, unsigned short><<<dim3(NQKV / 128, MTOT / 128, 1), 256, 0, stream>>>(
            xb, D_MODEL, 0, Wqkv_t, D_MODEL, 0, QKV, NQKV, 0, D_MODEL, bias_qkv, 1.f);
        // 2) S_b = Q_b @ K_b^T * scale    z-batched [2048 x 2048] x4
        gemm_bt<1, unsigned short><<<dim3(SEQ / 128, SEQ / 128, BATCH), 256, 0, stream>>>(
            QKV, NQKV, sQKV, QKV + D_MODEL, NQKV, sQKV, S, SEQ, sS, D_MODEL, nullptr, scale);
        // 3) A_b = S_b @ V_b^T            z-batched [2048 x 2048] x4
        gemm_bt<2, unsigned short><<<dim3(SEQ / 128, SEQ / 128, BATCH), 256, 0, stream>>>(
            S, SEQ, sS, QKV + 2 * D_MODEL, NQKV, sQKV, Abuf, SEQ, sS, SEQ, nullptr, 1.f);
        // 4) out = A @ Wfc_t^T + bias_fc  [8192 x 2048] f32 out, one launch
        gemm_bt<0, float><<<dim3(D_MODEL / 128, MTOT / 128, 1), 256, 0, stream>>>(
            Abuf, SEQ, 0, Wfc_t, D_MODEL, 0, out, D_MODEL, 0, SEQ, bias_fc, 1.f);
    } else {
        // Fallback: per-batch (round-2 proven path, ~110 MB)
        unsigned short* xb     = (unsigned short*)alloc((size_t)MTOT * D_MODEL * 2);
        unsigned short* Wqkv_t = (unsigned short*)alloc((size_t)NQKV * D_MODEL * 2);
        unsigned short* Wfc_t  = (unsigned short*)alloc((size_t)D_MODEL * D_MODEL * 2);
        unsigned short* QKVb   = (unsigned short*)alloc((size_t)SEQ * NQKV * 2);
        unsigned short* Sb     = (unsigned short*)alloc((size_t)SEQ * SEQ * 2);
        unsigned short* Ab     = (unsigned short*)alloc((size_t)SEQ * SEQ * 2);
        float* bias_qkv = (float*)alloc((size_t)NQKV * 4);
        float* bias_fc  = (float*)alloc((size_t)D_MODEL * 4);

        cvt_f32_bf16<<<(int)(nx / 1024), 256, 0, stream>>>(x, xb, nx);
        deint_wqkv<<<dim3(64, 64), 256, 0, stream>>>(Wqkv, Wqkv_t);
        transpose_wfc<<<dim3(64, 64), 256, 0, stream>>>(Wfc, Wfc_t);
        prep_bias<<<32, 256, 0, stream>>>(bqkv, bfc, bias_qkv, bias_fc);

        for (int b = 0; b < BATCH; ++b) {
            const unsigned short* xb_b = xb + (long long)b * SEQ * D_MODEL;
            float* out_b = out + (long long)b * SEQ * D_MODEL;
            gemm_bt<0, unsigned short><<<dim3(NQKV / 128, SEQ / 128, 1), 256, 0, stream>>>(
                xb_b, D_MODEL, 0, Wqkv_t, D_MODEL, 0, QKVb, NQKV, 0, D_MODEL, bias_qkv, 1.f);
            gemm_bt<1, unsigned short><<<dim3(SEQ / 128, SEQ / 128, 1), 256, 0, stream>>>(
                QKVb, NQKV, 0, QKVb + D_MODEL, NQKV, 0, Sb, SEQ, 0, D_MODEL, nullptr, scale);
            gemm_bt<2, unsigned short><<<dim3(SEQ / 128, SEQ / 128, 1), 256, 0, stream>>>(
                Sb, SEQ, 0, QKVb + 2 * D_MODEL, NQKV, 0, Ab, SEQ, 0, SEQ, nullptr, 1.f);
            gemm_bt<0, float><<<dim3(D_MODEL / 128, SEQ / 128, 1), 256, 0, stream>>>(
                Ab, SEQ, 0, Wfc_t, D_MODEL, 0, out_b, D_MODEL, 0, SEQ, bias_fc, 1.f);
        }
    }
}

// Round 4
// 714.944 us; speedup vs baseline: 1.5883x; 1.0895x over previous
//
#include <hip/hip_runtime.h>

#define D_MODEL 2048
#define SEQ     2048
#define BATCH   4
#define MTOT    (BATCH * SEQ)   // 8192
#define NQKV    (3 * D_MODEL)   // 6144

typedef __attribute__((ext_vector_type(8))) short bf16x8;
typedef __attribute__((ext_vector_type(8))) unsigned short ushort8;
typedef __attribute__((ext_vector_type(4))) float floatx4;

__device__ __forceinline__ unsigned short f2b(float f) {
    unsigned x = __builtin_bit_cast(unsigned, f);
    x += 0x7fffu + ((x >> 16) & 1u);   // round-to-nearest-even
    return (unsigned short)(x >> 16);
}

__device__ __forceinline__ void storeC(float* p, float v) { *p = v; }
__device__ __forceinline__ void storeC(unsigned short* p, float v) { *p = f2b(v); }

__device__ __forceinline__ void gload_lds16(const void* g, void* l) {
    __builtin_amdgcn_global_load_lds(
        (const __attribute__((address_space(1))) void*)g,
        (__attribute__((address_space(3))) void*)l,
        16, 0, 0);
}

// ---------------------------------------------------------------------------
// BT GEMM (z-batched): C[m,n] = (sum_k A[m,k]*B[n,k]) (+bias[n]) (*scale)
// A,B bf16 k-major. 128x128 tile, BK=64 as two 128x32 sub-tiles (full-line
// fetches, half the barriers), 256 thr (4 waves, 4x4 mfma 16x16x32).
// GROUP_M=8 rasterization swizzle (gridDim.y must be a multiple of 8).
// EPI: 0 = +bias[n], 1 = *scale, 2 = plain.  CT: float or ushort output.
// ---------------------------------------------------------------------------
template <int EPI, typename CT>
__global__ __launch_bounds__(256) void gemm_bt(
    const unsigned short* __restrict__ A, int lda, long long strA,
    const unsigned short* __restrict__ B, int ldb, long long strB,
    CT* __restrict__ C, int ldc, long long strC,
    int K, const float* __restrict__ bias, float scale)
{
    __shared__ __align__(16) unsigned short As[128 * 64];  // 2 sub-tiles of 128x32
    __shared__ __align__(16) unsigned short Bs[128 * 64];

    const int t = threadIdx.x;
    const int bz = blockIdx.z;
    A += (long long)bz * strA;
    B += (long long)bz * strB;
    C += (long long)bz * strC;

    // GROUP_M=8 swizzle: consecutive blocks sweep 8 m-tiles x all n-tiles
    const int gx = gridDim.x;
    const int lin = blockIdx.y * gx + blockIdx.x;
    const int per = 8 * gx;
    const int grp = lin / per;
    const int rem = lin - grp * per;
    const long long tM = (long long)(grp * 8 + (rem & 7)) * 128;
    const long long tN = (long long)(rem >> 3) * 128;

    // staging: thread t covers row (t>>2) (+64 for j=1), k-chunk (t&3)*8
    // within a 128x32 sub-tile; LDS slot = sub*4096 + j*2048 + t*8 elems.
    const int ldr = t >> 2;
    const int kof = (t & 3) * 8;
    const unsigned short* ga = A + (tM + ldr) * lda + kof;
    const unsigned short* gb = B + (tN + ldr) * ldb + kof;
    unsigned short* lAs = &As[(t >> 6) * 512];   // wave-uniform base
    unsigned short* lBs = &Bs[(t >> 6) * 512];
    const long long lda64 = (long long)64 * lda;
    const long long ldb64 = (long long)64 * ldb;

    const int l    = t & 63;
    const int w    = t >> 6;
    const int wm   = (w >> 1) * 64;
    const int wn   = (w & 1) * 64;
    const int quad = l >> 4;
    const int r16  = l & 15;

    floatx4 acc[4][4];
#pragma unroll
    for (int i = 0; i < 4; ++i)
#pragma unroll
        for (int j = 0; j < 4; ++j)
            acc[i][j] = (floatx4){0.f, 0.f, 0.f, 0.f};

    for (int k0 = 0; k0 < K; k0 += 64) {
#pragma unroll
        for (int ks = 0; ks < 2; ++ks)
#pragma unroll
            for (int j = 0; j < 2; ++j) {
                gload_lds16(ga + j * lda64 + k0 + ks * 32, lAs + ks * 4096 + j * 2048);
                gload_lds16(gb + j * ldb64 + k0 + ks * 32, lBs + ks * 4096 + j * 2048);
            }
        __syncthreads();

#pragma unroll
        for (int ks = 0; ks < 2; ++ks) {
            bf16x8 af[4], bfr[4];
#pragma unroll
            for (int mi = 0; mi < 4; ++mi)
                af[mi] = *(const bf16x8*)&As[ks * 4096 + (wm + mi * 16 + r16) * 32 + quad * 8];
#pragma unroll
            for (int ni = 0; ni < 4; ++ni)
                bfr[ni] = *(const bf16x8*)&Bs[ks * 4096 + (wn + ni * 16 + r16) * 32 + quad * 8];
#pragma unroll
            for (int mi = 0; mi < 4; ++mi)
#pragma unroll
                for (int ni = 0; ni < 4; ++ni)
                    acc[mi][ni] = __builtin_amdgcn_mfma_f32_16x16x32_bf16(
                        af[mi], bfr[ni], acc[mi][ni], 0, 0, 0);
        }
        __syncthreads();
    }

    // C/D layout: col = lane&15, row = (lane>>4)*4 + reg
#pragma unroll
    for (int mi = 0; mi < 4; ++mi) {
#pragma unroll
        for (int ni = 0; ni < 4; ++ni) {
            const long long row = tM + wm + mi * 16 + quad * 4;
            const int col = (int)tN + wn + ni * 16 + r16;
            float badd = 0.f;
            if (EPI == 0) badd = bias[col];
#pragma unroll
            for (int r = 0; r < 4; ++r) {
                float v = acc[mi][ni][r] + badd;
                if (EPI == 1) v *= scale;
                storeC(&C[(row + r) * ldc + col], v);
            }
        }
    }
}

// f32 -> bf16 bulk convert, 8 elems/thread (n divisible by 2048)
__global__ void cvt_f32_bf16(const float* __restrict__ in,
                             unsigned short* __restrict__ out, long long n)
{
    long long i = ((long long)blockIdx.x * 256 + threadIdx.x) * 8;
    if (i + 7 < n) {
        float4 a = *(const float4*)(in + i);
        float4 b = *(const float4*)(in + i + 4);
        ushort8 o = {f2b(a.x), f2b(a.y), f2b(a.z), f2b(a.w),
                     f2b(b.x), f2b(b.y), f2b(b.z), f2b(b.w)};
        *(ushort8*)(out + i) = o;
    }
}

// W_qkv f32 [2048, 6144] (f = 3*d + sel fastest) -> Wqkv_t bf16 [6144, 2048],
// Wqkv_t[sel*2048 + d][k] = W_qkv[k][3*d + sel].  Tile: 64 k x 32 d (96 cols).
__global__ void deint_wqkv(const float* __restrict__ W,
                           unsigned short* __restrict__ Wt)
{
    __shared__ unsigned short t2[96][72];   // row stride 144B (16B-aligned)
    const int d0 = blockIdx.x * 32;
    const int k0 = blockIdx.y * 64;
    const int t = threadIdx.x;

#pragma unroll
    for (int it = 0; it < 24; ++it) {
        int i = t + it * 256;               // 0..6143 over 64 rows x 96 cols
        int r = i / 96, c = i - r * 96;
        t2[c][r] = f2b(W[(long long)(k0 + r) * NQKV + 3 * d0 + c]);
    }
    __syncthreads();

#pragma unroll
    for (int rnd = 0; rnd < 3; ++rnd) {
        int c  = (t >> 3) + rnd * 32;       // 0..95
        int kc = t & 7;
        int dx = c / 3, sel = c - 3 * dx;
        *(ushort8*)&Wt[(long long)(sel * 2048 + d0 + dx) * D_MODEL + k0 + kc * 8] =
            *(const ushort8*)&t2[c][kc * 8];
    }
}

// W_fc f32 [2048, 2048] -> Wfc_t bf16, Wfc_t[n][k] = W_fc[k][n]. Tile 64x64.
__global__ void transpose_wfc(const float* __restrict__ W,
                              unsigned short* __restrict__ Wt)
{
    __shared__ unsigned short t2[64][72];
    const int n0 = blockIdx.x * 64;
    const int k0 = blockIdx.y * 64;
    const int t = threadIdx.x;

#pragma unroll
    for (int it = 0; it < 16; ++it) {
        int i = t + it * 256;               // 64 rows x 64 cols
        int r = i >> 6, c = i & 63;
        t2[c][r] = f2b(W[(long long)(k0 + r) * D_MODEL + n0 + c]);
    }
    __syncthreads();

#pragma unroll
    for (int rnd = 0; rnd < 2; ++rnd) {
        int c  = (t >> 3) + rnd * 32;
        int kc = t & 7;
        *(ushort8*)&Wt[(long long)(n0 + c) * D_MODEL + k0 + kc * 8] =
            *(const ushort8*)&t2[c][kc * 8];
    }
}

// bias deinterleave (f32 -> f32): bias_qkv_t[sel*2048+d] = bqkv[3*d+sel]
__global__ void prep_bias(const float* __restrict__ bqkv,
                          const float* __restrict__ bfc,
                          float* __restrict__ bias_qkv_t,
                          float* __restrict__ bias_fc)
{
    int i = blockIdx.x * 256 + threadIdx.x;
    if (i < NQKV) {
        int sel = i >> 11, d = i & 2047;
        bias_qkv_t[i] = bqkv[3 * d + sel];
    } else if (i < NQKV + D_MODEL) {
        bias_fc[i - NQKV] = bfc[i - NQKV];
    }
}

extern "C" void kernel_launch(void* const* d_in, const int* in_sizes, int n_in,
                              void* d_out, int out_size, void* d_ws, size_t ws_size,
                              hipStream_t stream)
{
    (void)in_sizes; (void)n_in; (void)out_size;

    const float* x    = (const float*)d_in[0];
    const float* Wqkv = (const float*)d_in[1];
    const float* bqkv = (const float*)d_in[2];
    const float* Wfc  = (const float*)d_in[3];
    const float* bfc  = (const float*)d_in[4];
    float* out = (float*)d_out;

    char* ws = (char*)d_ws;
    size_t off = 0;
    auto alloc = [&](size_t bytes) {
        void* p = ws + off;
        off += (bytes + 255) & ~(size_t)255;
        return p;
    };

    const float scale = 0.02209708691207961f;  // 2048^-0.5
    const long long nx = (long long)MTOT * D_MODEL;  // 16.8M elems

    const size_t NEED_BATCHED = (size_t)(33554432ull + 8388608ull + 25165824ull
                                + 100663296ull + 33554432ull + 65536ull);

    if (ws_size >= NEED_BATCHED) {
        unsigned short* xb     = (unsigned short*)alloc((size_t)MTOT * D_MODEL * 2);
        unsigned short* Wfc_t  = (unsigned short*)alloc((size_t)D_MODEL * D_MODEL * 2);
        unsigned short* Wqkv_t = (unsigned short*)alloc((size_t)NQKV * D_MODEL * 2);
        unsigned short* QKV    = (unsigned short*)alloc((size_t)MTOT * NQKV * 2);
        unsigned short* S      = (unsigned short*)alloc((size_t)BATCH * SEQ * SEQ * 2);
        float* bias_qkv = (float*)alloc((size_t)NQKV * 4);
        float* bias_fc  = (float*)alloc((size_t)D_MODEL * 4);
        unsigned short* Abuf = xb;   // xb dead after stage 1

        cvt_f32_bf16<<<(int)(nx / 2048), 256, 0, stream>>>(x, xb, nx);
        deint_wqkv<<<dim3(64, 32), 256, 0, stream>>>(Wqkv, Wqkv_t);
        transpose_wfc<<<dim3(32, 32), 256, 0, stream>>>(Wfc, Wfc_t);
        prep_bias<<<32, 256, 0, stream>>>(bqkv, bfc, bias_qkv, bias_fc);

        const long long sQKV = (long long)SEQ * NQKV;
        const long long sS   = (long long)SEQ * SEQ;

        // 1) QKV = xb @ Wqkv_t^T + bias   [8192 x 6144]
        gemm_bt<0, unsigned short><<<dim3(NQKV / 128, MTOT / 128, 1), 256, 0, stream>>>(
            xb, D_MODEL, 0, Wqkv_t, D_MODEL, 0, QKV, NQKV, 0, D_MODEL, bias_qkv, 1.f);
        // 2) S_b = Q_b @ K_b^T * scale    z-batched [2048 x 2048] x4
        gemm_bt<1, unsigned short><<<dim3(SEQ / 128, SEQ / 128, BATCH), 256, 0, stream>>>(
            QKV, NQKV, sQKV, QKV + D_MODEL, NQKV, sQKV, S, SEQ, sS, D_MODEL, nullptr, scale);
        // 3) A_b = S_b @ V_b^T            z-batched [2048 x 2048] x4
        gemm_bt<2, unsigned short><<<dim3(SEQ / 128, SEQ / 128, BATCH), 256, 0, stream>>>(
            S, SEQ, sS, QKV + 2 * D_MODEL, NQKV, sQKV, Abuf, SEQ, sS, SEQ, nullptr, 1.f);
        // 4) out = A @ Wfc_t^T + bias_fc  [8192 x 2048] f32 out
        gemm_bt<0, float><<<dim3(D_MODEL / 128, MTOT / 128, 1), 256, 0, stream>>>(
            Abuf, SEQ, 0, Wfc_t, D_MODEL, 0, out, D_MODEL, 0, SEQ, bias_fc, 1.f);
    } else {
        // Fallback: per-batch (~110 MB)
        unsigned short* xb     = (unsigned short*)alloc((size_t)MTOT * D_MODEL * 2);
        unsigned short* Wqkv_t = (unsigned short*)alloc((size_t)NQKV * D_MODEL * 2);
        unsigned short* Wfc_t  = (unsigned short*)alloc((size_t)D_MODEL * D_MODEL * 2);
        unsigned short* QKVb   = (unsigned short*)alloc((size_t)SEQ * NQKV * 2);
        unsigned short* Sb     = (unsigned short*)alloc((size_t)SEQ * SEQ * 2);
        unsigned short* Ab     = (unsigned short*)alloc((size_t)SEQ * SEQ * 2);
        float* bias_qkv = (float*)alloc((size_t)NQKV * 4);
        float* bias_fc  = (float*)alloc((size_t)D_MODEL * 4);

        cvt_f32_bf16<<<(int)(nx / 2048), 256, 0, stream>>>(x, xb, nx);
        deint_wqkv<<<dim3(64, 32), 256, 0, stream>>>(Wqkv, Wqkv_t);
        transpose_wfc<<<dim3(32, 32), 256, 0, stream>>>(Wfc, Wfc_t);
        prep_bias<<<32, 256, 0, stream>>>(bqkv, bfc, bias_qkv, bias_fc);

        for (int b = 0; b < BATCH; ++b) {
            const unsigned short* xb_b = xb + (long long)b * SEQ * D_MODEL;
            float* out_b = out + (long long)b * SEQ * D_MODEL;
            gemm_bt<0, unsigned short><<<dim3(NQKV / 128, SEQ / 128, 1), 256, 0, stream>>>(
                xb_b, D_MODEL, 0, Wqkv_t, D_MODEL, 0, QKVb, NQKV, 0, D_MODEL, bias_qkv, 1.f);
            gemm_bt<1, unsigned short><<<dim3(SEQ / 128, SEQ / 128, 1), 256, 0, stream>>>(
                QKVb, NQKV, 0, QKVb + D_MODEL, NQKV, 0, Sb, SEQ, 0, D_MODEL, nullptr, scale);
            gemm_bt<2, unsigned short><<<dim3(SEQ / 128, SEQ / 128, 1), 256, 0, stream>>>(
                Sb, SEQ, 0, QKVb + 2 * D_MODEL, NQKV, 0, Ab, SEQ, 0, SEQ, nullptr, 1.f);
            gemm_bt<0, float><<<dim3(D_MODEL / 128, SEQ / 128, 1), 256, 0, stream>>>(
                Ab, SEQ, 0, Wfc_t, D_MODEL, 0, out_b, D_MODEL, 0, SEQ, bias_fc, 1.f);
        }
    }
}

// Round 5
// 686.500 us; speedup vs baseline: 1.6541x; 1.0414x over previous
//
#include <hip/hip_runtime.h>

#define D_MODEL 2048
#define SEQ     2048
#define BATCH   4
#define MTOT    (BATCH * SEQ)   // 8192
#define NQKV    (3 * D_MODEL)   // 6144

typedef __attribute__((ext_vector_type(8))) short bf16x8;
typedef __attribute__((ext_vector_type(8))) unsigned short ushort8;
typedef __attribute__((ext_vector_type(4))) float floatx4;

__device__ __forceinline__ unsigned short f2b(float f) {
    unsigned x = __builtin_bit_cast(unsigned, f);
    x += 0x7fffu + ((x >> 16) & 1u);   // round-to-nearest-even
    return (unsigned short)(x >> 16);
}

__device__ __forceinline__ void storeC(float* p, float v) { *p = v; }
__device__ __forceinline__ void storeC(unsigned short* p, float v) { *p = f2b(v); }

__device__ __forceinline__ void gload_lds16(const void* g, void* l) {
    __builtin_amdgcn_global_load_lds(
        (const __attribute__((address_space(1))) void*)g,
        (__attribute__((address_space(3))) void*)l,
        16, 0, 0);
}

// ---------------------------------------------------------------------------
// BT GEMM (z-batched): C[m,n] = (sum_k A[m,k]*B[n,k]) (+bias[n]) (*scale)
// A,B bf16 k-major. 128x128 tile, BK=64 as two 128x32 sub-tiles (full 128B-line
// fetches per row, half the barriers), 256 thr (4 waves, 4x4 mfma 16x16x32).
// NOTE: no rasterization swizzle — default raster + XCD round-robin measured
// 3x better L2 reuse than GROUP_M=8 (R4: FETCH 213->616 MB with swizzle).
// EPI: 0 = +bias[n], 1 = *scale, 2 = plain.  CT: float or ushort output.
// ---------------------------------------------------------------------------
template <int EPI, typename CT>
__global__ __launch_bounds__(256) void gemm_bt(
    const unsigned short* __restrict__ A, int lda, long long strA,
    const unsigned short* __restrict__ B, int ldb, long long strB,
    CT* __restrict__ C, int ldc, long long strC,
    int K, const float* __restrict__ bias, float scale)
{
    __shared__ __align__(16) unsigned short As[128 * 64];  // 2 sub-tiles of 128x32
    __shared__ __align__(16) unsigned short Bs[128 * 64];

    const int t = threadIdx.x;
    const int bz = blockIdx.z;
    A += (long long)bz * strA;
    B += (long long)bz * strB;
    C += (long long)bz * strC;

    const long long tM = (long long)blockIdx.y * 128;
    const long long tN = (long long)blockIdx.x * 128;

    // staging: thread t covers row (t>>2) (+64 for j=1), k-chunk (t&3)*8
    // within a 128x32 sub-tile; LDS slot = sub*4096 + j*2048 + t*8 elems.
    const int ldr = t >> 2;
    const int kof = (t & 3) * 8;
    const unsigned short* ga = A + (tM + ldr) * lda + kof;
    const unsigned short* gb = B + (tN + ldr) * ldb + kof;
    unsigned short* lAs = &As[(t >> 6) * 512];   // wave-uniform base
    unsigned short* lBs = &Bs[(t >> 6) * 512];
    const long long lda64 = (long long)64 * lda;
    const long long ldb64 = (long long)64 * ldb;

    const int l    = t & 63;
    const int w    = t >> 6;
    const int wm   = (w >> 1) * 64;
    const int wn   = (w & 1) * 64;
    const int quad = l >> 4;
    const int r16  = l & 15;

    floatx4 acc[4][4];
#pragma unroll
    for (int i = 0; i < 4; ++i)
#pragma unroll
        for (int j = 0; j < 4; ++j)
            acc[i][j] = (floatx4){0.f, 0.f, 0.f, 0.f};

    for (int k0 = 0; k0 < K; k0 += 64) {
#pragma unroll
        for (int ks = 0; ks < 2; ++ks)
#pragma unroll
            for (int j = 0; j < 2; ++j) {
                gload_lds16(ga + j * lda64 + k0 + ks * 32, lAs + ks * 4096 + j * 2048);
                gload_lds16(gb + j * ldb64 + k0 + ks * 32, lBs + ks * 4096 + j * 2048);
            }
        __syncthreads();

#pragma unroll
        for (int ks = 0; ks < 2; ++ks) {
            bf16x8 af[4], bfr[4];
#pragma unroll
            for (int mi = 0; mi < 4; ++mi)
                af[mi] = *(const bf16x8*)&As[ks * 4096 + (wm + mi * 16 + r16) * 32 + quad * 8];
#pragma unroll
            for (int ni = 0; ni < 4; ++ni)
                bfr[ni] = *(const bf16x8*)&Bs[ks * 4096 + (wn + ni * 16 + r16) * 32 + quad * 8];
#pragma unroll
            for (int mi = 0; mi < 4; ++mi)
#pragma unroll
                for (int ni = 0; ni < 4; ++ni)
                    acc[mi][ni] = __builtin_amdgcn_mfma_f32_16x16x32_bf16(
                        af[mi], bfr[ni], acc[mi][ni], 0, 0, 0);
        }
        __syncthreads();
    }

    // C/D layout: col = lane&15, row = (lane>>4)*4 + reg
#pragma unroll
    for (int mi = 0; mi < 4; ++mi) {
#pragma unroll
        for (int ni = 0; ni < 4; ++ni) {
            const long long row = tM + wm + mi * 16 + quad * 4;
            const int col = (int)tN + wn + ni * 16 + r16;
            float badd = 0.f;
            if (EPI == 0) badd = bias[col];
#pragma unroll
            for (int r = 0; r < 4; ++r) {
                float v = acc[mi][ni][r] + badd;
                if (EPI == 1) v *= scale;
                storeC(&C[(row + r) * ldc + col], v);
            }
        }
    }
}

// f32 -> bf16 bulk convert, 8 elems/thread (n divisible by 2048)
__global__ void cvt_f32_bf16(const float* __restrict__ in,
                             unsigned short* __restrict__ out, long long n)
{
    long long i = ((long long)blockIdx.x * 256 + threadIdx.x) * 8;
    if (i + 7 < n) {
        float4 a = *(const float4*)(in + i);
        float4 b = *(const float4*)(in + i + 4);
        ushort8 o = {f2b(a.x), f2b(a.y), f2b(a.z), f2b(a.w),
                     f2b(b.x), f2b(b.y), f2b(b.z), f2b(b.w)};
        *(ushort8*)(out + i) = o;
    }
}

// W_qkv f32 [2048, 6144] (f = 3*d + sel fastest) -> Wqkv_t bf16 [6144, 2048],
// Wqkv_t[sel*2048 + d][k] = W_qkv[k][3*d + sel].  Tile: 64 k x 32 d (96 cols).
__global__ void deint_wqkv(const float* __restrict__ W,
                           unsigned short* __restrict__ Wt)
{
    __shared__ unsigned short t2[96][72];   // row stride 144B (16B-aligned)
    const int d0 = blockIdx.x * 32;
    const int k0 = blockIdx.y * 64;
    const int t = threadIdx.x;

#pragma unroll
    for (int it = 0; it < 24; ++it) {
        int i = t + it * 256;               // 0..6143 over 64 rows x 96 cols
        int r = i / 96, c = i - r * 96;
        t2[c][r] = f2b(W[(long long)(k0 + r) * NQKV + 3 * d0 + c]);
    }
    __syncthreads();

#pragma unroll
    for (int rnd = 0; rnd < 3; ++rnd) {
        int c  = (t >> 3) + rnd * 32;       // 0..95
        int kc = t & 7;
        int dx = c / 3, sel = c - 3 * dx;
        *(ushort8*)&Wt[(long long)(sel * 2048 + d0 + dx) * D_MODEL + k0 + kc * 8] =
            *(const ushort8*)&t2[c][kc * 8];
    }
}

// W_fc f32 [2048, 2048] -> Wfc_t bf16, Wfc_t[n][k] = W_fc[k][n]. Tile 64x64.
__global__ void transpose_wfc(const float* __restrict__ W,
                              unsigned short* __restrict__ Wt)
{
    __shared__ unsigned short t2[64][72];
    const int n0 = blockIdx.x * 64;
    const int k0 = blockIdx.y * 64;
    const int t = threadIdx.x;

#pragma unroll
    for (int it = 0; it < 16; ++it) {
        int i = t + it * 256;               // 64 rows x 64 cols
        int r = i >> 6, c = i & 63;
        t2[c][r] = f2b(W[(long long)(k0 + r) * D_MODEL + n0 + c]);
    }
    __syncthreads();

#pragma unroll
    for (int rnd = 0; rnd < 2; ++rnd) {
        int c  = (t >> 3) + rnd * 32;
        int kc = t & 7;
        *(ushort8*)&Wt[(long long)(n0 + c) * D_MODEL + k0 + kc * 8] =
            *(const ushort8*)&t2[c][kc * 8];
    }
}

// bias deinterleave (f32 -> f32): bias_qkv_t[sel*2048+d] = bqkv[3*d+sel]
__global__ void prep_bias(const float* __restrict__ bqkv,
                          const float* __restrict__ bfc,
                          float* __restrict__ bias_qkv_t,
                          float* __restrict__ bias_fc)
{
    int i = blockIdx.x * 256 + threadIdx.x;
    if (i < NQKV) {
        int sel = i >> 11, d = i & 2047;
        bias_qkv_t[i] = bqkv[3 * d + sel];
    } else if (i < NQKV + D_MODEL) {
        bias_fc[i - NQKV] = bfc[i - NQKV];
    }
}

extern "C" void kernel_launch(void* const* d_in, const int* in_sizes, int n_in,
                              void* d_out, int out_size, void* d_ws, size_t ws_size,
                              hipStream_t stream)
{
    (void)in_sizes; (void)n_in; (void)out_size;

    const float* x    = (const float*)d_in[0];
    const float* Wqkv = (const float*)d_in[1];
    const float* bqkv = (const float*)d_in[2];
    const float* Wfc  = (const float*)d_in[3];
    const float* bfc  = (const float*)d_in[4];
    float* out = (float*)d_out;

    char* ws = (char*)d_ws;
    size_t off = 0;
    auto alloc = [&](size_t bytes) {
        void* p = ws + off;
        off += (bytes + 255) & ~(size_t)255;
        return p;
    };

    const float scale = 0.02209708691207961f;  // 2048^-0.5
    const long long nx = (long long)MTOT * D_MODEL;  // 16.8M elems

    const size_t NEED_BATCHED = (size_t)(33554432ull + 8388608ull + 25165824ull
                                + 100663296ull + 33554432ull + 65536ull);

    if (ws_size >= NEED_BATCHED) {
        unsigned short* xb     = (unsigned short*)alloc((size_t)MTOT * D_MODEL * 2);
        unsigned short* Wfc_t  = (unsigned short*)alloc((size_t)D_MODEL * D_MODEL * 2);
        unsigned short* Wqkv_t = (unsigned short*)alloc((size_t)NQKV * D_MODEL * 2);
        unsigned short* QKV    = (unsigned short*)alloc((size_t)MTOT * NQKV * 2);
        unsigned short* S      = (unsigned short*)alloc((size_t)BATCH * SEQ * SEQ * 2);
        float* bias_qkv = (float*)alloc((size_t)NQKV * 4);
        float* bias_fc  = (float*)alloc((size_t)D_MODEL * 4);
        unsigned short* Abuf = xb;   // xb dead after stage 1

        cvt_f32_bf16<<<(int)(nx / 2048), 256, 0, stream>>>(x, xb, nx);
        deint_wqkv<<<dim3(64, 32), 256, 0, stream>>>(Wqkv, Wqkv_t);
        transpose_wfc<<<dim3(32, 32), 256, 0, stream>>>(Wfc, Wfc_t);
        prep_bias<<<32, 256, 0, stream>>>(bqkv, bfc, bias_qkv, bias_fc);

        const long long sQKV = (long long)SEQ * NQKV;
        const long long sS   = (long long)SEQ * SEQ;

        // 1) QKV = xb @ Wqkv_t^T + bias   [8192 x 6144]
        gemm_bt<0, unsigned short><<<dim3(NQKV / 128, MTOT / 128, 1), 256, 0, stream>>>(
            xb, D_MODEL, 0, Wqkv_t, D_MODEL, 0, QKV, NQKV, 0, D_MODEL, bias_qkv, 1.f);
        // 2) S_b = Q_b @ K_b^T * scale    z-batched [2048 x 2048] x4
        gemm_bt<1, unsigned short><<<dim3(SEQ / 128, SEQ / 128, BATCH), 256, 0, stream>>>(
            QKV, NQKV, sQKV, QKV + D_MODEL, NQKV, sQKV, S, SEQ, sS, D_MODEL, nullptr, scale);
        // 3) A_b = S_b @ V_b^T            z-batched [2048 x 2048] x4
        gemm_bt<2, unsigned short><<<dim3(SEQ / 128, SEQ / 128, BATCH), 256, 0, stream>>>(
            S, SEQ, sS, QKV + 2 * D_MODEL, NQKV, sQKV, Abuf, SEQ, sS, SEQ, nullptr, 1.f);
        // 4) out = A @ Wfc_t^T + bias_fc  [8192 x 2048] f32 out
        gemm_bt<0, float><<<dim3(D_MODEL / 128, MTOT / 128, 1), 256, 0, stream>>>(
            Abuf, SEQ, 0, Wfc_t, D_MODEL, 0, out, D_MODEL, 0, SEQ, bias_fc, 1.f);
    } else {
        // Fallback: per-batch (~110 MB)
        unsigned short* xb     = (unsigned short*)alloc((size_t)MTOT * D_MODEL * 2);
        unsigned short* Wqkv_t = (unsigned short*)alloc((size_t)NQKV * D_MODEL * 2);
        unsigned short* Wfc_t  = (unsigned short*)alloc((size_t)D_MODEL * D_MODEL * 2);
        unsigned short* QKVb   = (unsigned short*)alloc((size_t)SEQ * NQKV * 2);
        unsigned short* Sb     = (unsigned short*)alloc((size_t)SEQ * SEQ * 2);
        unsigned short* Ab     = (unsigned short*)alloc((size_t)SEQ * SEQ * 2);
        float* bias_qkv = (float*)alloc((size_t)NQKV * 4);
        float* bias_fc  = (float*)alloc((size_t)D_MODEL * 4);

        cvt_f32_bf16<<<(int)(nx / 2048), 256, 0, stream>>>(x, xb, nx);
        deint_wqkv<<<dim3(64, 32), 256, 0, stream>>>(Wqkv, Wqkv_t);
        transpose_wfc<<<dim3(32, 32), 256, 0, stream>>>(Wfc, Wfc_t);
        prep_bias<<<32, 256, 0, stream>>>(bqkv, bfc, bias_qkv, bias_fc);

        for (int b = 0; b < BATCH; ++b) {
            const unsigned short* xb_b = xb + (long long)b * SEQ * D_MODEL;
            float* out_b = out + (long long)b * SEQ * D_MODEL;
            gemm_bt<0, unsigned short><<<dim3(NQKV / 128, SEQ / 128, 1), 256, 0, stream>>>(
                xb_b, D_MODEL, 0, Wqkv_t, D_MODEL, 0, QKVb, NQKV, 0, D_MODEL, bias_qkv, 1.f);
            gemm_bt<1, unsigned short><<<dim3(SEQ / 128, SEQ / 128, 1), 256, 0, stream>>>(
                QKVb, NQKV, 0, QKVb + D_MODEL, NQKV, 0, Sb, SEQ, 0, D_MODEL, nullptr, scale);
            gemm_bt<2, unsigned short><<<dim3(SEQ / 128, SEQ / 128, 1), 256, 0, stream>>>(
                Sb, SEQ, 0, QKVb + 2 * D_MODEL, NQKV, 0, Ab, SEQ, 0, SEQ, nullptr, 1.f);
            gemm_bt<0, float><<<dim3(D_MODEL / 128, SEQ / 128, 1), 256, 0, stream>>>(
                Ab, SEQ, 0, Wfc_t, D_MODEL, 0, out_b, D_MODEL, 0, SEQ, bias_fc, 1.f);
        }
    }
}